// Round 19
// baseline (222.114 us; speedup 1.0000x reference)
//
#include <hip/hip_runtime.h>
#include <math.h>

#define N_NODES 50000
#define N_EDGES 600000
#define D 128
#define KTOT 384    // 3*D  (k: [n1 | n2 | feat])
#define NCOLS 512   // 4*D  (gate-interleaved cols: c' = 4c+g)

#define SCAN_CHUNK 512
#define SCAN_NB ((N_NODES + SCAN_CHUNK - 1) / SCAN_CHUNK)   // 98

#define GEMM_ROWB ((N_NODES + 255) / 256)    // 196 row panels (256 rows each)
#define GEMM_NWG  (GEMM_ROWB * 8)            // 1568 blocks, 8 col-blocks
#define NXCD 8
#define KHALF 192                            // K per LDS stage

// binned CSR build
#define BSHIFT 10
#define BSIZE (1 << BSHIFT)
#define NBUCKETS ((N_NODES + BSIZE - 1) >> BSHIFT)           // 49
#define PA_NB 512
#define PA_CHUNK ((N_EDGES + PA_NB - 1) / PA_NB)             // 1172

typedef unsigned int u32;
typedef unsigned short u16;

typedef __attribute__((ext_vector_type(8))) short bf16x8;   // 8 bf16 (4 VGPRs)
typedef __attribute__((ext_vector_type(4))) float f32x4;

__device__ __forceinline__ float bits2f(u32 u) {
    float f; __builtin_memcpy(&f, &u, 4);
    return f;
}
__device__ __forceinline__ u16 f2b(float f) {   // RNE bf16
    u32 u; __builtin_memcpy(&u, &f, 4);
    u32 r = (u + 0x7fffu + ((u >> 16) & 1u)) >> 16;
    return (u16)r;
}

// ---------------------------------------------------------------------------
__global__ void fill_sentinel(float* __restrict__ p, long n, float v) {
    long i = (long)blockIdx.x * blockDim.x + threadIdx.x;
    long stride = (long)gridDim.x * blockDim.x;
    for (; i < n; i += stride) p[i] = v;
}

// ---------------------------------------------------------------------------
// Front: zero degree counters AND convert feat fp32 -> bf16 into fb16[N][128].
// ---------------------------------------------------------------------------
__global__ void front(const float* __restrict__ feat, u16* __restrict__ fb16,
                      u32* __restrict__ offz) {
    long stride = (long)gridDim.x * blockDim.x;
    long t0 = (long)blockIdx.x * blockDim.x + threadIdx.x;
    for (long i = t0; i < 2 * N_NODES; i += stride) offz[i] = 0u;
    for (long i = t0; i < (long)N_NODES * (D / 4); i += stride) {
        int n = (int)(i >> 5), j4 = (int)(i & 31);
        float4 v = *(const float4*)(feat + (size_t)n * D + j4 * 4);
        ushort4 o;
        o.x = f2b(v.x); o.y = f2b(v.y); o.z = f2b(v.z); o.w = f2b(v.w);
        *(ushort4*)(fb16 + ((size_t)n << 7) + j4 * 4) = o;
    }
}

// ---------------------------------------------------------------------------
// CSR build step 1: degree count (both directions).
// ---------------------------------------------------------------------------
__global__ void count_both(const int* __restrict__ esrc, const int* __restrict__ edst,
                           int* __restrict__ cnt1, int* __restrict__ cnt2) {
    int e = blockIdx.x * blockDim.x + threadIdx.x;
    if (e < N_EDGES) {
        atomicAdd(&cnt1[edst[e]], 1);
        atomicAdd(&cnt2[esrc[e]], 1);
    }
}

// Phase 1: per-block chunk sums. grid (SCAN_NB, 2), 256 threads, 2 elems/thread.
__global__ void scan_partial(const int* __restrict__ off, int* __restrict__ bsum) {
    int dir = blockIdx.y, bx = blockIdx.x, t = threadIdx.x;
    const int* a = off + (size_t)dir * N_NODES;
    int i0 = bx * SCAN_CHUNK + 2 * t;
    int s = 0;
    if (i0 < N_NODES) s += a[i0];
    if (i0 + 1 < N_NODES) s += a[i0 + 1];
    __shared__ int red[256];
    red[t] = s;
    __syncthreads();
    for (int d = 128; d > 0; d >>= 1) {
        if (t < d) red[t] += red[t + d];
        __syncthreads();
    }
    if (t == 0) bsum[dir * SCAN_NB + bx] = red[0];
}

// Phase 2: exclusive scan of the two bsum segments (one block, two halves).
__global__ void scan_bsums(int* __restrict__ bsum) {
    __shared__ int part[256];
    int t = threadIdx.x;
    int i = t & 127, dir = t >> 7;
    int v = (i < SCAN_NB) ? bsum[dir * SCAN_NB + i] : 0;
    part[t] = v;
    __syncthreads();
    for (int d = 1; d < 128; d <<= 1) {
        int add = (i >= d) ? part[t - d] : 0;
        __syncthreads();
        part[t] += add;
        __syncthreads();
    }
    if (i < SCAN_NB) bsum[dir * SCAN_NB + i] = part[t] - v;  // exclusive
}

// Phase 3: in-place exclusive scan of each chunk + block base -> off[n]=start(n).
__global__ void scan_final(int* __restrict__ off, const int* __restrict__ bsum) {
    int dir = blockIdx.y, bx = blockIdx.x, t = threadIdx.x;
    int* a = off + (size_t)dir * N_NODES;
    int base = bsum[dir * SCAN_NB + bx];
    int i0 = bx * SCAN_CHUNK + 2 * t;
    int e0 = (i0 < N_NODES) ? a[i0] : 0;
    int e1 = (i0 + 1 < N_NODES) ? a[i0 + 1] : 0;
    __shared__ int part[256];
    int v = e0 + e1;
    part[t] = v;
    __syncthreads();
    for (int d = 1; d < 256; d <<= 1) {
        int add = (t >= d) ? part[t - d] : 0;
        __syncthreads();
        part[t] += add;
        __syncthreads();
    }
    int tb = base + part[t] - v;   // exclusive prefix for this thread
    if (i0 < N_NODES) a[i0] = tb;
    if (i0 + 1 < N_NODES) a[i0 + 1] = tb + e0;
}

// ---------------------------------------------------------------------------
// Bucket bounds (off holds starts; NOT consumed anywhere downstream).
// ---------------------------------------------------------------------------
__global__ void init_buckets(const int* __restrict__ off1, const int* __restrict__ off2,
                             int* __restrict__ bks) {
    // layout: bks[0..49]=start1, [64..112]=fill1, [128..177]=start2, [192..240]=fill2
    int t = threadIdx.x;
    if (t <= NBUCKETS) {
        int n = t << BSHIFT;
        int s1 = (t == NBUCKETS) ? N_EDGES : off1[n];
        int s2 = (t == NBUCKETS) ? N_EDGES : off2[n];
        bks[t] = s1;
        bks[128 + t] = s2;
        if (t < NBUCKETS) { bks[64 + t] = s1; bks[192 + t] = s2; }
    }
}

// ---------------------------------------------------------------------------
// Phase A (both dirs fused, blockIdx.y = dir): partition edges into coarse
// buckets via LDS histogram + staging; flush per-bucket runs to tmp.
// Staged entry embeds the bucket id -> flush is ONE LDS read, no search.
// ---------------------------------------------------------------------------
__global__ __launch_bounds__(256)
void partA(const int* __restrict__ esrc, const int* __restrict__ edst,
           const float* __restrict__ ew, int* __restrict__ bks,
           uint2* __restrict__ tmp1, uint2* __restrict__ tmp2) {
    __shared__ int lcnt[NBUCKETS];
    __shared__ int lbase[NBUCKETS + 1];
    __shared__ int gbase[NBUCKETS];
    __shared__ uint2 stage[PA_CHUNK];
    int dir = blockIdx.y;
    const int* key = dir ? esrc : edst;
    const int* nbr = dir ? edst : esrc;
    int* bucketFill = bks + (dir ? 192 : 64);
    uint2* tmp = dir ? tmp2 : tmp1;

    int t = threadIdx.x;
    int e0 = blockIdx.x * PA_CHUNK;
    int e1 = min(e0 + PA_CHUNK, N_EDGES);
    if (t < NBUCKETS) lcnt[t] = 0;
    __syncthreads();
    for (int e = e0 + t; e < e1; e += 256)
        atomicAdd(&lcnt[key[e] >> BSHIFT], 1);
    __syncthreads();
    if (t == 0) {
        int s = 0;
        for (int b = 0; b < NBUCKETS; ++b) { lbase[b] = s; s += lcnt[b]; }
        lbase[NBUCKETS] = s;
    }
    __syncthreads();
    if (t < NBUCKETS) {
        gbase[t] = atomicAdd(&bucketFill[t], lcnt[t]);
        lcnt[t] = 0;    // reuse as fill
    }
    __syncthreads();
    for (int e = e0 + t; e < e1; e += 256) {
        int k = key[e];
        int b = k >> BSHIFT;
        int i = lbase[b] + atomicAdd(&lcnt[b], 1);
        u32 wb = (u32)f2b(ew[e]);
        stage[i] = make_uint2(((u32)k << 16) | (u32)nbr[e], ((u32)b << 16) | wb);
    }
    __syncthreads();
    int total = lbase[NBUCKETS];
    for (int i = t; i < total; i += 256) {
        uint2 v = stage[i];
        int b = (int)(v.y >> 16);
        tmp[gbase[b] + (i - lbase[b])] = make_uint2(v.x, v.y & 0xffffu);
    }
}

// ---------------------------------------------------------------------------
// Phase B: ONE block per (bucket, dir). LDS-claimed slots; all writes of a
// bucket flow through one CU -> one XCD L2 -> ~1x write amplification.
// ---------------------------------------------------------------------------
__global__ __launch_bounds__(256)
void partB(const uint2* __restrict__ tmp1, const uint2* __restrict__ tmp2,
           const int* __restrict__ bks,
           const int* __restrict__ off1, const int* __restrict__ off2,
           u32* __restrict__ csr1, u32* __restrict__ csr2) {
    __shared__ int lcnt[BSIZE];
    __shared__ int loff[BSIZE];
    int dir = blockIdx.y;
    const uint2* tmp = dir ? tmp2 : tmp1;
    const int* bucketStart = bks + dir * 128;
    const int* off = dir ? off2 : off1;
    u32* csr = dir ? csr2 : csr1;

    int b = blockIdx.x;
    int s = bucketStart[b], e = bucketStart[b + 1];
    int nbase = b << BSHIFT;
    for (int i = threadIdx.x; i < BSIZE; i += 256) {
        lcnt[i] = 0;
        int nn = nbase + i;
        loff[i] = (nn < N_NODES) ? off[nn] : 0;
    }
    __syncthreads();
    for (int i = s + (int)threadIdx.x; i < e; i += 256) {
        uint2 v = tmp[i];
        int li = (v.x >> 16) & (BSIZE - 1);
        int p = loff[li] + atomicAdd(&lcnt[li], 1);
        csr[p] = ((v.x & 0xffffu) << 16) | (v.y & 0xffffu);
    }
}

// ---------------------------------------------------------------------------
// Fused gather-aggregate. One wave per (node, dir); TWO edges per half-wave
// step, 8 edges in flight. 128-thread blocks. off holds STARTS.
// ---------------------------------------------------------------------------
__global__ __launch_bounds__(128)
void gather_both(u16* __restrict__ Ah2, const u16* __restrict__ fb16,
                 const int* __restrict__ off1, const u32* __restrict__ csr1,
                 const int* __restrict__ off2, const u32* __restrict__ csr2) {
    int gw = (blockIdx.x * blockDim.x + threadIdx.x) >> 6;
    int lane = threadIdx.x & 63;
    if (gw >= 2 * N_NODES) return;
    int dir = (gw >= N_NODES);
    int n = dir ? gw - N_NODES : gw;
    const int* off = dir ? off2 : off1;
    const u32* csr = dir ? csr2 : csr1;
    int start = off[n];
    int end = (n + 1 < N_NODES) ? off[n + 1] : N_EDGES;
    int half = lane >> 5;
    int hl = lane & 31;
    const u16* fbl = fb16 + hl * 4;
    float a0 = 0.f, a1 = 0.f, a2 = 0.f, a3 = 0.f, sw = 0.f;
    int p = start;
    for (; p + 7 < end; p += 8) {
        u32 cA = csr[p + half],     cB = csr[p + 2 + half];
        u32 cC = csr[p + 4 + half], cD = csr[p + 6 + half];
        uint2 vA = *(const uint2*)(fbl + ((size_t)(cA >> 16) << 7));
        uint2 vB = *(const uint2*)(fbl + ((size_t)(cB >> 16) << 7));
        uint2 vC = *(const uint2*)(fbl + ((size_t)(cC >> 16) << 7));
        uint2 vD = *(const uint2*)(fbl + ((size_t)(cD >> 16) << 7));
        float wA = bits2f(cA << 16), wB = bits2f(cB << 16);
        float wC = bits2f(cC << 16), wD = bits2f(cD << 16);
        a0 += bits2f(vA.x << 16) * wA + bits2f(vB.x << 16) * wB
            + bits2f(vC.x << 16) * wC + bits2f(vD.x << 16) * wD;
        a1 += bits2f(vA.x & 0xffff0000u) * wA + bits2f(vB.x & 0xffff0000u) * wB
            + bits2f(vC.x & 0xffff0000u) * wC + bits2f(vD.x & 0xffff0000u) * wD;
        a2 += bits2f(vA.y << 16) * wA + bits2f(vB.y << 16) * wB
            + bits2f(vC.y << 16) * wC + bits2f(vD.y << 16) * wD;
        a3 += bits2f(vA.y & 0xffff0000u) * wA + bits2f(vB.y & 0xffff0000u) * wB
            + bits2f(vC.y & 0xffff0000u) * wC + bits2f(vD.y & 0xffff0000u) * wD;
        sw += wA + wB + wC + wD;
    }
    for (; p + 3 < end; p += 4) {
        u32 cA = csr[p + half], cB = csr[p + 2 + half];
        uint2 vA = *(const uint2*)(fbl + ((size_t)(cA >> 16) << 7));
        uint2 vB = *(const uint2*)(fbl + ((size_t)(cB >> 16) << 7));
        float wA = bits2f(cA << 16), wB = bits2f(cB << 16);
        a0 += bits2f(vA.x << 16) * wA + bits2f(vB.x << 16) * wB;
        a1 += bits2f(vA.x & 0xffff0000u) * wA + bits2f(vB.x & 0xffff0000u) * wB;
        a2 += bits2f(vA.y << 16) * wA + bits2f(vB.y << 16) * wB;
        a3 += bits2f(vA.y & 0xffff0000u) * wA + bits2f(vB.y & 0xffff0000u) * wB;
        sw += wA + wB;
    }
    for (; p < end; p += 2) {
        u32 c = (p + half < end) ? csr[p + half] : 0u;   // c=0 -> w=0, row 0
        uint2 v = *(const uint2*)(fbl + ((size_t)(c >> 16) << 7));
        float w = bits2f(c << 16);
        a0 += bits2f(v.x << 16) * w;
        a1 += bits2f(v.x & 0xffff0000u) * w;
        a2 += bits2f(v.y << 16) * w;
        a3 += bits2f(v.y & 0xffff0000u) * w;
        sw += w;
    }
    a0 += __shfl_xor(a0, 32);
    a1 += __shfl_xor(a1, 32);
    a2 += __shfl_xor(a2, 32);
    a3 += __shfl_xor(a3, 32);
    sw += __shfl_xor(sw, 32);
    if (lane < 32) {
        float inv = (sw > 0.f) ? 1.f / sw : 0.f;
        if (!isfinite(inv)) inv = 0.f;
        uint2 o;
        o.x = ((u32)f2b(a1 * inv) << 16) | (u32)f2b(a0 * inv);
        o.y = ((u32)f2b(a3 * inv) << 16) | (u32)f2b(a2 * inv);
        *(uint2*)(Ah2 + ((size_t)n << 8) + dir * 128 + hl * 4) = o;
    }
}

// ---------------------------------------------------------------------------
// Weight folding: M1 = W_ih[:, :128] @ W1 ; M2 = W_ih[:, 128:] @ W2 (fp32).
// ---------------------------------------------------------------------------
__global__ void compute_M(const float* __restrict__ W_ih,
                          const float* __restrict__ W1,
                          const float* __restrict__ W2,
                          float* __restrict__ M1, float* __restrict__ M2) {
    int r = blockIdx.x;          // 0..383
    int k = threadIdx.x;         // 0..127
    int which = blockIdx.y;
    const float* Wsel = which ? W2 : W1;
    const float* ih = W_ih + (size_t)r * (2 * D) + which * D;
    float acc = 0.f;
    for (int j = 0; j < D; ++j) acc += ih[j] * Wsel[j * D + k];
    (which ? M2 : M1)[r * D + k] = acc;
}

// ---------------------------------------------------------------------------
// Bt [512 cols][384 k] bf16, k-contiguous rows. Col c' = 4c+g:
//   g=0: r-sum rows c (M1|M2|W_hh); g=1: z-sum rows c+128;
//   g=2: gi_n rows c+256 (M1|M2|0); g=3: gh_n (0|0|W_hh row c+256)
// ---------------------------------------------------------------------------
__global__ void fill_Bt(const float* __restrict__ M1, const float* __restrict__ M2,
                        const float* __restrict__ W_hh, u16* __restrict__ Bt) {
    int idx = blockIdx.x * blockDim.x + threadIdx.x;
    if (idx >= NCOLS * KTOT) return;
    int cp = idx / KTOT;
    int k  = idx - cp * KTOT;
    int c = cp >> 2, g = cp & 3;
    float v = 0.f;
    if (g <= 1) {
        int r = c + (g == 1 ? 128 : 0);
        v = (k < 128) ? M1[r * D + k]
          : (k < 256) ? M2[r * D + (k - 128)]
                      : W_hh[r * D + (k - 256)];
    } else if (g == 2) {
        int r = c + 256;
        v = (k < 128) ? M1[r * D + k]
          : (k < 256) ? M2[r * D + (k - 128)] : 0.f;
    } else {
        v = (k >= 256) ? W_hh[(c + 256) * D + (k - 256)] : 0.f;
    }
    if (!isfinite(v)) v = 0.f;
    Bt[idx] = f2b(v);
}

// ---------------------------------------------------------------------------
// MFMA GEMM + fused GRU, v9: wave tile 64x64 (4 m-fragments, acc 4x4 f32x4 =
// 64 AGPR) -> per k-step 16 MFMAs vs 4 LDS + 4 global loads (2x the arith
// intensity of v8). Block = 4 waves stacked = 256 rows x 64 cols; grid
// 196x8 = 1568 XCD-swizzled. Two-half B staging in 24 KB LDS (XOR swizzle on
// full offset both sides, rule #21); depth-2 A pipeline (cur/next); epilogue
// aliases the B LDS, 4 m-iterations.
// ---------------------------------------------------------------------------
#define LOAD_A(m, k) ((k) < 8 ? *(const bf16x8*)(aP[m] + (k) * 32) \
                              : *(const bf16x8*)(fP[m] + ((k) - 8) * 32))

__global__ __launch_bounds__(256)
void gemm_gru_mfma(const u16* __restrict__ Ah2, const u16* __restrict__ fb16,
                   const u16* __restrict__ Bt, const float* __restrict__ feat,
                   const float* __restrict__ b_ih, const float* __restrict__ b_hh,
                   float* __restrict__ out) {
    __shared__ __align__(16) char smem[64 * KHALF * 2];  // 24 KB: B half / epi
    float (*epi)[16][65] = (float(*)[16][65])smem;       // aliases B (dead later)

    int bid = blockIdx.x;
    int wgid = (bid % NXCD) * (GEMM_NWG / NXCD) + bid / NXCD;   // bijective
    int rowp = wgid >> 3;
    int colb = wgid & 7;
    int tid = threadIdx.x, lane = tid & 63, wid = tid >> 6;
    int mw = rowp * 256 + wid * 64;         // wave row (node) base (64 rows)
    int nw = colb * 64;                     // block gate-col base (all waves)
    int rif = lane & 15, kg = lane >> 4;

    // staging geometry (per half): each thread 6 x b128
    int scol = tid >> 2;                   // 0..63
    int sq   = tid & 3;                    // 0..3 -> 48-k quarter
    u32 sbase = (u32)scol * (KHALF * 2) + (u32)sq * 96;
    u32 sxor  = (u32)((scol & 7) << 4);
    const u16* ssrc0 = Bt + (size_t)(nw + scol) * KTOT + sq * 48;

    // B read: col base within half; XOR applied to FULL offset (rule #21).
    u32 bCol[4], bXor[4];
    #pragma unroll
    for (int n = 0; n < 4; ++n) {
        u32 col = n * 16 + rif;
        bCol[n] = col * (KHALF * 2) + kg * 16;
        bXor[n] = (col & 7) << 4;
    }

    f32x4 acc[4][4];
    #pragma unroll
    for (int m = 0; m < 4; ++m)
        #pragma unroll
        for (int n = 0; n < 4; ++n)
            acc[m][n] = (f32x4){0.f, 0.f, 0.f, 0.f};

    const u16* aP[4];
    const u16* fP[4];
    #pragma unroll
    for (int m = 0; m < 4; ++m) {
        int arow = min(mw + m * 16 + rif, N_NODES - 1);
        aP[m] = Ah2 + ((size_t)arow << 8) + kg * 8;
        fP[m] = fb16 + ((size_t)arow << 7) + kg * 8;
    }

    // stage half 0
    #pragma unroll
    for (int i = 0; i < 6; ++i) {
        bf16x8 v = *(const bf16x8*)(ssrc0 + i * 8);
        *(bf16x8*)(smem + ((sbase + i * 16) ^ sxor)) = v;
    }

    // depth-2 A pipeline: load step 0 now
    bf16x8 acur[4], anxt[4];
    #pragma unroll
    for (int m = 0; m < 4; ++m) acur[m] = LOAD_A(m, 0);

    __syncthreads();   // half 0 ready

    #pragma unroll
    for (int ks = 0; ks < 6; ++ks) {
        if (ks + 1 < 12) {
            #pragma unroll
            for (int m = 0; m < 4; ++m) anxt[m] = LOAD_A(m, ks + 1);
        }
        bf16x8 bfr[4];
        #pragma unroll
        for (int n = 0; n < 4; ++n)
            bfr[n] = *(const bf16x8*)(smem + ((bCol[n] + ks * 64) ^ bXor[n]));
        #pragma unroll
        for (int m = 0; m < 4; ++m)
            #pragma unroll
            for (int n = 0; n < 4; ++n)
                acc[m][n] = __builtin_amdgcn_mfma_f32_16x16x32_bf16(
                    acur[m], bfr[n], acc[m][n], 0, 0, 0);
        #pragma unroll
        for (int m = 0; m < 4; ++m) acur[m] = anxt[m];
    }

    __syncthreads();   // half-0 reads done; safe to overwrite

    // stage half 1
    #pragma unroll
    for (int i = 0; i < 6; ++i) {
        bf16x8 v = *(const bf16x8*)(ssrc0 + KHALF + i * 8);
        *(bf16x8*)(smem + ((sbase + i * 16) ^ sxor)) = v;
    }
    __syncthreads();   // half 1 ready

    #pragma unroll
    for (int ks = 6; ks < 12; ++ks) {
        if (ks + 1 < 12) {
            #pragma unroll
            for (int m = 0; m < 4; ++m) anxt[m] = LOAD_A(m, ks + 1);
        }
        bf16x8 bfr[4];
        #pragma unroll
        for (int n = 0; n < 4; ++n)
            bfr[n] = *(const bf16x8*)(smem + ((bCol[n] + (ks - 6) * 64) ^ bXor[n]));
        #pragma unroll
        for (int m = 0; m < 4; ++m)
            #pragma unroll
            for (int n = 0; n < 4; ++n)
                acc[m][n] = __builtin_amdgcn_mfma_f32_16x16x32_bf16(
                    acur[m], bfr[n], acc[m][n], 0, 0, 0);
        #pragma unroll
        for (int m = 0; m < 4; ++m) acur[m] = anxt[m];
    }

    // ---- epilogue: de-interleave gates + GRU (epi aliases B; barrier fences) ----
    int rc0 = nw >> 2;          // wave real-col base (16 real cols)
    int erow = lane >> 2;       // 0..15
    int g4 = lane & 3;          // 4 real cols per lane
    int cbase = rc0 + g4 * 4;
    float4 bi_r = *(const float4*)(b_ih + cbase);
    float4 bh_r = *(const float4*)(b_hh + cbase);
    float4 bi_z = *(const float4*)(b_ih + cbase + 128);
    float4 bh_z = *(const float4*)(b_hh + cbase + 128);
    float4 bi_n = *(const float4*)(b_ih + cbase + 256);
    float4 bh_n = *(const float4*)(b_hh + cbase + 256);

    #pragma unroll
    for (int m = 0; m < 4; ++m) {
        __syncthreads();    // fence: B reads done (m=0) / prev epi reads done
        #pragma unroll
        for (int n = 0; n < 4; ++n)
            #pragma unroll
            for (int reg = 0; reg < 4; ++reg)
                epi[wid][kg * 4 + reg][n * 16 + rif] = acc[m][n][reg];
        __syncthreads();

        float4 q0 = *(const float4*)&epi[wid][erow][g4 * 16 + 0];
        float4 q1 = *(const float4*)&epi[wid][erow][g4 * 16 + 4];
        float4 q2 = *(const float4*)&epi[wid][erow][g4 * 16 + 8];
        float4 q3 = *(const float4*)&epi[wid][erow][g4 * 16 + 12];

        int node = mw + m * 16 + erow;
        if (node < N_NODES) {
            float4 f = *(const float4*)(feat + (size_t)node * D + cbase);
            float4 res;
            {
                float r = 1.f / (1.f + __expf(-(q0.x + bi_r.x + bh_r.x)));
                float z = 1.f / (1.f + __expf(-(q0.y + bi_z.x + bh_z.x)));
                float ng = tanhf(q0.z + bi_n.x + r * (q0.w + bh_n.x));
                res.x = (1.f - z) * ng + z * f.x;
            }
            {
                float r = 1.f / (1.f + __expf(-(q1.x + bi_r.y + bh_r.y)));
                float z = 1.f / (1.f + __expf(-(q1.y + bi_z.y + bh_z.y)));
                float ng = tanhf(q1.z + bi_n.y + r * (q1.w + bh_n.y));
                res.y = (1.f - z) * ng + z * f.y;
            }
            {
                float r = 1.f / (1.f + __expf(-(q2.x + bi_r.z + bh_r.z)));
                float z = 1.f / (1.f + __expf(-(q2.y + bi_z.z + bh_z.z)));
                float ng = tanhf(q2.z + bi_n.z + r * (q2.w + bh_n.z));
                res.z = (1.f - z) * ng + z * f.z;
            }
            {
                float r = 1.f / (1.f + __expf(-(q3.x + bi_r.w + bh_r.w)));
                float z = 1.f / (1.f + __expf(-(q3.y + bi_z.w + bh_z.w)));
                float ng = tanhf(q3.z + bi_n.w + r * (q3.w + bh_n.w));
                res.w = (1.f - z) * ng + z * f.w;
            }
            *(float4*)(out + (size_t)node * D + cbase) = res;
        }
    }
}

// ===========================================================================
extern "C" void kernel_launch(void* const* d_in, const int* in_sizes, int n_in,
                              void* d_out, int out_size, void* d_ws, size_t ws_size,
                              hipStream_t stream) {
    const float* feat = (const float*)d_in[0];
    const int*   esrc = (const int*)d_in[1];
    const int*   edst = (const int*)d_in[2];
    const float* ew   = (const float*)d_in[3];
    const float* W1   = (const float*)d_in[4];
    const float* W2   = (const float*)d_in[5];
    const float* W_ih = (const float*)d_in[6];
    const float* W_hh = (const float*)d_in[7];
    const float* b_ih = (const float*)d_in[8];
    const float* b_hh = (const float*)d_in[9];
    float* out = (float*)d_out;

    const size_t AH2_ELEMS = (size_t)N_NODES * 256;  // u16
    const size_t FB_ELEMS  = (size_t)N_NODES * 128;  // u16
    const size_t needWords = (AH2_ELEMS + FB_ELEMS) / 2 + 2 * N_NODES
                           + 2 * (size_t)N_EDGES          // csr1+csr2
                           + 4 * (size_t)N_EDGES          // tmp1+tmp2 (uint2)
                           + 512 + 2 * (size_t)KTOT * D + (NCOLS * KTOT) / 2;
    if (ws_size < needWords * 4) {
        fill_sentinel<<<512, 256, 0, stream>>>(out, (long)out_size, 12345.0f);
        return;
    }

    u16*   Ah2  = (u16*)d_ws;
    u16*   fb16 = Ah2 + AH2_ELEMS;
    int*   off1 = (int*)(fb16 + FB_ELEMS);
    int*   off2 = off1 + N_NODES;
    u32*   csr1 = (u32*)(off2 + N_NODES);
    u32*   csr2 = csr1 + N_EDGES;
    uint2* tmp1 = (uint2*)(csr2 + N_EDGES);
    uint2* tmp2 = tmp1 + N_EDGES;
    int*   bsum = (int*)(tmp2 + N_EDGES);    // 256
    int*   bks  = bsum + 256;                // 256
    float* M1   = (float*)(bks + 256);
    float* M2   = M1 + KTOT * D;
    u16*   Bt   = (u16*)(M2 + KTOT * D);

    const int EB = (N_EDGES + 255) / 256;

    front<<<2048, 256, 0, stream>>>(feat, fb16, (u32*)off1);
    count_both<<<EB, 256, 0, stream>>>(esrc, edst, off1, off2);
    scan_partial<<<dim3(SCAN_NB, 2), 256, 0, stream>>>(off1, bsum);
    scan_bsums<<<1, 256, 0, stream>>>(bsum);
    scan_final<<<dim3(SCAN_NB, 2), 256, 0, stream>>>(off1, bsum);

    init_buckets<<<1, 64, 0, stream>>>(off1, off2, bks);
    partA<<<dim3(PA_NB, 2), 256, 0, stream>>>(esrc, edst, ew, bks, tmp1, tmp2);
    partB<<<dim3(NBUCKETS, 2), 256, 0, stream>>>(
        tmp1, tmp2, bks, off1, off2, csr1, csr2);

    gather_both<<<(2 * N_NODES * 64 + 127) / 128, 128, 0, stream>>>(
        Ah2, fb16, off1, csr1, off2, csr2);

    compute_M<<<dim3(KTOT, 2), 128, 0, stream>>>(W_ih, W1, W2, M1, M2);
    fill_Bt<<<(NCOLS * KTOT + 255) / 256, 256, 0, stream>>>(M1, M2, W_hh, Bt);

    gemm_gru_mfma<<<GEMM_NWG, 256, 0, stream>>>(Ah2, fb16, Bt, feat, b_ih, b_hh, out);
}

// Round 20
// 208.174 us; speedup vs baseline: 1.0670x; 1.0670x over previous
//
#include <hip/hip_runtime.h>
#include <math.h>

#define N_NODES 50000
#define N_EDGES 600000
#define D 128
#define KTOT 384    // 3*D  (k: [n1 | n2 | feat])
#define NCOLS 512   // 4*D  (gate-interleaved cols: c' = 4c+g)

#define SCAN_CHUNK 512
#define SCAN_NB ((N_NODES + SCAN_CHUNK - 1) / SCAN_CHUNK)   // 98

#define GEMM_ROWB ((N_NODES + 127) / 128)    // 391 row panels
#define GEMM_NWG  (GEMM_ROWB * 8)            // 3128 blocks, 8 col-blocks
#define NXCD 8
#define KHALF 192                            // K per LDS stage

// binned CSR build
#define BSHIFT 10
#define BSIZE (1 << BSHIFT)
#define NBUCKETS ((N_NODES + BSIZE - 1) >> BSHIFT)           // 49
#define PA_NB 512
#define PA_CHUNK ((N_EDGES + PA_NB - 1) / PA_NB)             // 1172

typedef unsigned int u32;
typedef unsigned short u16;

typedef __attribute__((ext_vector_type(8))) short bf16x8;   // 8 bf16 (4 VGPRs)
typedef __attribute__((ext_vector_type(4))) float f32x4;

__device__ __forceinline__ float bits2f(u32 u) {
    float f; __builtin_memcpy(&f, &u, 4);
    return f;
}
__device__ __forceinline__ u16 f2b(float f) {   // RNE bf16
    u32 u; __builtin_memcpy(&u, &f, 4);
    u32 r = (u + 0x7fffu + ((u >> 16) & 1u)) >> 16;
    return (u16)r;
}

// ---------------------------------------------------------------------------
__global__ void fill_sentinel(float* __restrict__ p, long n, float v) {
    long i = (long)blockIdx.x * blockDim.x + threadIdx.x;
    long stride = (long)gridDim.x * blockDim.x;
    for (; i < n; i += stride) p[i] = v;
}

// ---------------------------------------------------------------------------
// Front: zero degree counters AND convert feat fp32 -> bf16 into fb16[N][128].
// ---------------------------------------------------------------------------
__global__ void front(const float* __restrict__ feat, u16* __restrict__ fb16,
                      u32* __restrict__ offz) {
    long stride = (long)gridDim.x * blockDim.x;
    long t0 = (long)blockIdx.x * blockDim.x + threadIdx.x;
    for (long i = t0; i < 2 * N_NODES; i += stride) offz[i] = 0u;
    for (long i = t0; i < (long)N_NODES * (D / 4); i += stride) {
        int n = (int)(i >> 5), j4 = (int)(i & 31);
        float4 v = *(const float4*)(feat + (size_t)n * D + j4 * 4);
        ushort4 o;
        o.x = f2b(v.x); o.y = f2b(v.y); o.z = f2b(v.z); o.w = f2b(v.w);
        *(ushort4*)(fb16 + ((size_t)n << 7) + j4 * 4) = o;
    }
}

// ---------------------------------------------------------------------------
// CSR build step 1: degree count (both directions).
// ---------------------------------------------------------------------------
__global__ void count_both(const int* __restrict__ esrc, const int* __restrict__ edst,
                           int* __restrict__ cnt1, int* __restrict__ cnt2) {
    int e = blockIdx.x * blockDim.x + threadIdx.x;
    if (e < N_EDGES) {
        atomicAdd(&cnt1[edst[e]], 1);
        atomicAdd(&cnt2[esrc[e]], 1);
    }
}

// Phase 1: per-block chunk sums. grid (SCAN_NB, 2), 256 threads, 2 elems/thread.
__global__ void scan_partial(const int* __restrict__ off, int* __restrict__ bsum) {
    int dir = blockIdx.y, bx = blockIdx.x, t = threadIdx.x;
    const int* a = off + (size_t)dir * N_NODES;
    int i0 = bx * SCAN_CHUNK + 2 * t;
    int s = 0;
    if (i0 < N_NODES) s += a[i0];
    if (i0 + 1 < N_NODES) s += a[i0 + 1];
    __shared__ int red[256];
    red[t] = s;
    __syncthreads();
    for (int d = 128; d > 0; d >>= 1) {
        if (t < d) red[t] += red[t + d];
        __syncthreads();
    }
    if (t == 0) bsum[dir * SCAN_NB + bx] = red[0];
}

// Phase 2: exclusive scan of the two bsum segments (one block, two halves).
__global__ void scan_bsums(int* __restrict__ bsum) {
    __shared__ int part[256];
    int t = threadIdx.x;
    int i = t & 127, dir = t >> 7;
    int v = (i < SCAN_NB) ? bsum[dir * SCAN_NB + i] : 0;
    part[t] = v;
    __syncthreads();
    for (int d = 1; d < 128; d <<= 1) {
        int add = (i >= d) ? part[t - d] : 0;
        __syncthreads();
        part[t] += add;
        __syncthreads();
    }
    if (i < SCAN_NB) bsum[dir * SCAN_NB + i] = part[t] - v;  // exclusive
}

// Phase 3: in-place exclusive scan of each chunk + block base -> off[n]=start(n).
__global__ void scan_final(int* __restrict__ off, const int* __restrict__ bsum) {
    int dir = blockIdx.y, bx = blockIdx.x, t = threadIdx.x;
    int* a = off + (size_t)dir * N_NODES;
    int base = bsum[dir * SCAN_NB + bx];
    int i0 = bx * SCAN_CHUNK + 2 * t;
    int e0 = (i0 < N_NODES) ? a[i0] : 0;
    int e1 = (i0 + 1 < N_NODES) ? a[i0 + 1] : 0;
    __shared__ int part[256];
    int v = e0 + e1;
    part[t] = v;
    __syncthreads();
    for (int d = 1; d < 256; d <<= 1) {
        int add = (t >= d) ? part[t - d] : 0;
        __syncthreads();
        part[t] += add;
        __syncthreads();
    }
    int tb = base + part[t] - v;   // exclusive prefix for this thread
    if (i0 < N_NODES) a[i0] = tb;
    if (i0 + 1 < N_NODES) a[i0 + 1] = tb + e0;
}

// ---------------------------------------------------------------------------
// Bucket bounds (off holds starts; NOT consumed anywhere downstream).
// ---------------------------------------------------------------------------
__global__ void init_buckets(const int* __restrict__ off1, const int* __restrict__ off2,
                             int* __restrict__ bks) {
    // layout: bks[0..49]=start1, [64..112]=fill1, [128..177]=start2, [192..240]=fill2
    int t = threadIdx.x;
    if (t <= NBUCKETS) {
        int n = t << BSHIFT;
        int s1 = (t == NBUCKETS) ? N_EDGES : off1[n];
        int s2 = (t == NBUCKETS) ? N_EDGES : off2[n];
        bks[t] = s1;
        bks[128 + t] = s2;
        if (t < NBUCKETS) { bks[64 + t] = s1; bks[192 + t] = s2; }
    }
}

// ---------------------------------------------------------------------------
// Phase A (both dirs fused, blockIdx.y = dir): partition edges into coarse
// buckets via LDS histogram + staging; flush per-bucket runs to tmp.
// Staged entry embeds the bucket id -> flush is ONE LDS read, no search.
// ---------------------------------------------------------------------------
__global__ __launch_bounds__(256)
void partA(const int* __restrict__ esrc, const int* __restrict__ edst,
           const float* __restrict__ ew, int* __restrict__ bks,
           uint2* __restrict__ tmp1, uint2* __restrict__ tmp2) {
    __shared__ int lcnt[NBUCKETS];
    __shared__ int lbase[NBUCKETS + 1];
    __shared__ int gbase[NBUCKETS];
    __shared__ uint2 stage[PA_CHUNK];
    int dir = blockIdx.y;
    const int* key = dir ? esrc : edst;
    const int* nbr = dir ? edst : esrc;
    int* bucketFill = bks + (dir ? 192 : 64);
    uint2* tmp = dir ? tmp2 : tmp1;

    int t = threadIdx.x;
    int e0 = blockIdx.x * PA_CHUNK;
    int e1 = min(e0 + PA_CHUNK, N_EDGES);
    if (t < NBUCKETS) lcnt[t] = 0;
    __syncthreads();
    for (int e = e0 + t; e < e1; e += 256)
        atomicAdd(&lcnt[key[e] >> BSHIFT], 1);
    __syncthreads();
    if (t == 0) {
        int s = 0;
        for (int b = 0; b < NBUCKETS; ++b) { lbase[b] = s; s += lcnt[b]; }
        lbase[NBUCKETS] = s;
    }
    __syncthreads();
    if (t < NBUCKETS) {
        gbase[t] = atomicAdd(&bucketFill[t], lcnt[t]);
        lcnt[t] = 0;    // reuse as fill
    }
    __syncthreads();
    for (int e = e0 + t; e < e1; e += 256) {
        int k = key[e];
        int b = k >> BSHIFT;
        int i = lbase[b] + atomicAdd(&lcnt[b], 1);
        u32 wb = (u32)f2b(ew[e]);
        stage[i] = make_uint2(((u32)k << 16) | (u32)nbr[e], ((u32)b << 16) | wb);
    }
    __syncthreads();
    int total = lbase[NBUCKETS];
    for (int i = t; i < total; i += 256) {
        uint2 v = stage[i];
        int b = (int)(v.y >> 16);
        tmp[gbase[b] + (i - lbase[b])] = make_uint2(v.x, v.y & 0xffffu);
    }
}

// ---------------------------------------------------------------------------
// Phase B: ONE block per (bucket, dir). LDS-claimed slots; all writes of a
// bucket flow through one CU -> one XCD L2 -> ~1x write amplification.
// ---------------------------------------------------------------------------
__global__ __launch_bounds__(256)
void partB(const uint2* __restrict__ tmp1, const uint2* __restrict__ tmp2,
           const int* __restrict__ bks,
           const int* __restrict__ off1, const int* __restrict__ off2,
           u32* __restrict__ csr1, u32* __restrict__ csr2) {
    __shared__ int lcnt[BSIZE];
    __shared__ int loff[BSIZE];
    int dir = blockIdx.y;
    const uint2* tmp = dir ? tmp2 : tmp1;
    const int* bucketStart = bks + dir * 128;
    const int* off = dir ? off2 : off1;
    u32* csr = dir ? csr2 : csr1;

    int b = blockIdx.x;
    int s = bucketStart[b], e = bucketStart[b + 1];
    int nbase = b << BSHIFT;
    for (int i = threadIdx.x; i < BSIZE; i += 256) {
        lcnt[i] = 0;
        int nn = nbase + i;
        loff[i] = (nn < N_NODES) ? off[nn] : 0;
    }
    __syncthreads();
    for (int i = s + (int)threadIdx.x; i < e; i += 256) {
        uint2 v = tmp[i];
        int li = (v.x >> 16) & (BSIZE - 1);
        int p = loff[li] + atomicAdd(&lcnt[li], 1);
        csr[p] = ((v.x & 0xffffu) << 16) | (v.y & 0xffffu);
    }
}

// ---------------------------------------------------------------------------
// Fused gather-aggregate. One wave per (node, dir); TWO edges per half-wave
// step, 8 edges in flight. 128-thread blocks. off holds STARTS.
// ---------------------------------------------------------------------------
__global__ __launch_bounds__(128)
void gather_both(u16* __restrict__ Ah2, const u16* __restrict__ fb16,
                 const int* __restrict__ off1, const u32* __restrict__ csr1,
                 const int* __restrict__ off2, const u32* __restrict__ csr2) {
    int gw = (blockIdx.x * blockDim.x + threadIdx.x) >> 6;
    int lane = threadIdx.x & 63;
    if (gw >= 2 * N_NODES) return;
    int dir = (gw >= N_NODES);
    int n = dir ? gw - N_NODES : gw;
    const int* off = dir ? off2 : off1;
    const u32* csr = dir ? csr2 : csr1;
    int start = off[n];
    int end = (n + 1 < N_NODES) ? off[n + 1] : N_EDGES;
    int half = lane >> 5;
    int hl = lane & 31;
    const u16* fbl = fb16 + hl * 4;
    float a0 = 0.f, a1 = 0.f, a2 = 0.f, a3 = 0.f, sw = 0.f;
    int p = start;
    for (; p + 7 < end; p += 8) {
        u32 cA = csr[p + half],     cB = csr[p + 2 + half];
        u32 cC = csr[p + 4 + half], cD = csr[p + 6 + half];
        uint2 vA = *(const uint2*)(fbl + ((size_t)(cA >> 16) << 7));
        uint2 vB = *(const uint2*)(fbl + ((size_t)(cB >> 16) << 7));
        uint2 vC = *(const uint2*)(fbl + ((size_t)(cC >> 16) << 7));
        uint2 vD = *(const uint2*)(fbl + ((size_t)(cD >> 16) << 7));
        float wA = bits2f(cA << 16), wB = bits2f(cB << 16);
        float wC = bits2f(cC << 16), wD = bits2f(cD << 16);
        a0 += bits2f(vA.x << 16) * wA + bits2f(vB.x << 16) * wB
            + bits2f(vC.x << 16) * wC + bits2f(vD.x << 16) * wD;
        a1 += bits2f(vA.x & 0xffff0000u) * wA + bits2f(vB.x & 0xffff0000u) * wB
            + bits2f(vC.x & 0xffff0000u) * wC + bits2f(vD.x & 0xffff0000u) * wD;
        a2 += bits2f(vA.y << 16) * wA + bits2f(vB.y << 16) * wB
            + bits2f(vC.y << 16) * wC + bits2f(vD.y << 16) * wD;
        a3 += bits2f(vA.y & 0xffff0000u) * wA + bits2f(vB.y & 0xffff0000u) * wB
            + bits2f(vC.y & 0xffff0000u) * wC + bits2f(vD.y & 0xffff0000u) * wD;
        sw += wA + wB + wC + wD;
    }
    for (; p + 3 < end; p += 4) {
        u32 cA = csr[p + half], cB = csr[p + 2 + half];
        uint2 vA = *(const uint2*)(fbl + ((size_t)(cA >> 16) << 7));
        uint2 vB = *(const uint2*)(fbl + ((size_t)(cB >> 16) << 7));
        float wA = bits2f(cA << 16), wB = bits2f(cB << 16);
        a0 += bits2f(vA.x << 16) * wA + bits2f(vB.x << 16) * wB;
        a1 += bits2f(vA.x & 0xffff0000u) * wA + bits2f(vB.x & 0xffff0000u) * wB;
        a2 += bits2f(vA.y << 16) * wA + bits2f(vB.y << 16) * wB;
        a3 += bits2f(vA.y & 0xffff0000u) * wA + bits2f(vB.y & 0xffff0000u) * wB;
        sw += wA + wB;
    }
    for (; p < end; p += 2) {
        u32 c = (p + half < end) ? csr[p + half] : 0u;   // c=0 -> w=0, row 0
        uint2 v = *(const uint2*)(fbl + ((size_t)(c >> 16) << 7));
        float w = bits2f(c << 16);
        a0 += bits2f(v.x << 16) * w;
        a1 += bits2f(v.x & 0xffff0000u) * w;
        a2 += bits2f(v.y << 16) * w;
        a3 += bits2f(v.y & 0xffff0000u) * w;
        sw += w;
    }
    a0 += __shfl_xor(a0, 32);
    a1 += __shfl_xor(a1, 32);
    a2 += __shfl_xor(a2, 32);
    a3 += __shfl_xor(a3, 32);
    sw += __shfl_xor(sw, 32);
    if (lane < 32) {
        float inv = (sw > 0.f) ? 1.f / sw : 0.f;
        if (!isfinite(inv)) inv = 0.f;
        uint2 o;
        o.x = ((u32)f2b(a1 * inv) << 16) | (u32)f2b(a0 * inv);
        o.y = ((u32)f2b(a3 * inv) << 16) | (u32)f2b(a2 * inv);
        *(uint2*)(Ah2 + ((size_t)n << 8) + dir * 128 + hl * 4) = o;
    }
}

// ---------------------------------------------------------------------------
// Weight folding: M1 = W_ih[:, :128] @ W1 ; M2 = W_ih[:, 128:] @ W2 (fp32).
// ---------------------------------------------------------------------------
__global__ void compute_M(const float* __restrict__ W_ih,
                          const float* __restrict__ W1,
                          const float* __restrict__ W2,
                          float* __restrict__ M1, float* __restrict__ M2) {
    int r = blockIdx.x;          // 0..383
    int k = threadIdx.x;         // 0..127
    int which = blockIdx.y;
    const float* Wsel = which ? W2 : W1;
    const float* ih = W_ih + (size_t)r * (2 * D) + which * D;
    float acc = 0.f;
    for (int j = 0; j < D; ++j) acc += ih[j] * Wsel[j * D + k];
    (which ? M2 : M1)[r * D + k] = acc;
}

// ---------------------------------------------------------------------------
// Bt [512 cols][384 k] bf16, k-contiguous rows. Col c' = 4c+g:
//   g=0: r-sum rows c (M1|M2|W_hh); g=1: z-sum rows c+128;
//   g=2: gi_n rows c+256 (M1|M2|0); g=3: gh_n (0|0|W_hh row c+256)
// ---------------------------------------------------------------------------
__global__ void fill_Bt(const float* __restrict__ M1, const float* __restrict__ M2,
                        const float* __restrict__ W_hh, u16* __restrict__ Bt) {
    int idx = blockIdx.x * blockDim.x + threadIdx.x;
    if (idx >= NCOLS * KTOT) return;
    int cp = idx / KTOT;
    int k  = idx - cp * KTOT;
    int c = cp >> 2, g = cp & 3;
    float v = 0.f;
    if (g <= 1) {
        int r = c + (g == 1 ? 128 : 0);
        v = (k < 128) ? M1[r * D + k]
          : (k < 256) ? M2[r * D + (k - 128)]
                      : W_hh[r * D + (k - 256)];
    } else if (g == 2) {
        int r = c + 256;
        v = (k < 128) ? M1[r * D + k]
          : (k < 256) ? M2[r * D + (k - 128)] : 0.f;
    } else {
        v = (k >= 256) ? W_hh[(c + 256) * D + (k - 256)] : 0.f;
    }
    if (!isfinite(v)) v = 0.f;
    Bt[idx] = f2b(v);
}

// ---------------------------------------------------------------------------
// MFMA GEMM + fused GRU, v8b = round-18's proven v8 (32x64 wave tile, two-half
// B staging in 24 KB LDS, pow2-stride A tables, depth-4 A ring, XOR swizzle
// on full offset both sides) with epilogue barriers reduced: epi[wid] is
// per-wave, so only ONE block barrier is needed (fence B-buffer aliasing);
// intra-wave ds_write->ds_read ordering is wave-synchronous (lgkmcnt).
// ---------------------------------------------------------------------------
#define LOAD_A(m, k) ((k) < 8 ? *(const bf16x8*)(aP[m] + (k) * 32) \
                              : *(const bf16x8*)(fP[m] + ((k) - 8) * 32))

__global__ __launch_bounds__(256)
void gemm_gru_mfma(const u16* __restrict__ Ah2, const u16* __restrict__ fb16,
                   const u16* __restrict__ Bt, const float* __restrict__ feat,
                   const float* __restrict__ b_ih, const float* __restrict__ b_hh,
                   float* __restrict__ out) {
    __shared__ __align__(16) char smem[64 * KHALF * 2];  // 24 KB: B half / epi
    float (*epi)[16][65] = (float(*)[16][65])smem;       // aliases B (dead later)

    int bid = blockIdx.x;
    int wgid = (bid % NXCD) * (GEMM_NWG / NXCD) + bid / NXCD;   // bijective
    int rowp = wgid >> 3;
    int colb = wgid & 7;
    int tid = threadIdx.x, lane = tid & 63, wid = tid >> 6;
    int mw = rowp * 128 + wid * 32;         // wave row (node) base
    int nw = colb * 64;                     // block gate-col base (all waves)
    int rif = lane & 15, kg = lane >> 4;

    // staging geometry (per half): each thread 6 x b128
    int scol = tid >> 2;                   // 0..63
    int sq   = tid & 3;                    // 0..3 -> 48-k quarter
    u32 sbase = (u32)scol * (KHALF * 2) + (u32)sq * 96;
    u32 sxor  = (u32)((scol & 7) << 4);
    const u16* ssrc0 = Bt + (size_t)(nw + scol) * KTOT + sq * 48;

    // B read: col base within half; XOR applied to FULL offset (rule #21).
    u32 bCol[4], bXor[4];
    #pragma unroll
    for (int n = 0; n < 4; ++n) {
        u32 col = n * 16 + rif;
        bCol[n] = col * (KHALF * 2) + kg * 16;
        bXor[n] = (col & 7) << 4;
    }

    f32x4 acc[2][4];
    #pragma unroll
    for (int m = 0; m < 2; ++m)
        #pragma unroll
        for (int n = 0; n < 4; ++n)
            acc[m][n] = (f32x4){0.f, 0.f, 0.f, 0.f};

    const u16* aP[2];
    const u16* fP[2];
    #pragma unroll
    for (int m = 0; m < 2; ++m) {
        int arow = min(mw + m * 16 + rif, N_NODES - 1);
        aP[m] = Ah2 + ((size_t)arow << 8) + kg * 8;
        fP[m] = fb16 + ((size_t)arow << 7) + kg * 8;
    }

    // stage half 0
    #pragma unroll
    for (int i = 0; i < 6; ++i) {
        bf16x8 v = *(const bf16x8*)(ssrc0 + i * 8);
        *(bf16x8*)(smem + ((sbase + i * 16) ^ sxor)) = v;
    }

    // depth-4 A prefetch ring (fully unrolled -> static indices)
    bf16x8 abuf[4][2];
    #pragma unroll
    for (int s = 0; s < 3; ++s)
        #pragma unroll
        for (int m = 0; m < 2; ++m)
            abuf[s][m] = LOAD_A(m, s);

    __syncthreads();   // half 0 ready

    #pragma unroll
    for (int ks = 0; ks < 6; ++ks) {
        if (ks + 3 < KTOT / 32) {
            #pragma unroll
            for (int m = 0; m < 2; ++m)
                abuf[(ks + 3) & 3][m] = LOAD_A(m, ks + 3);
        }
        bf16x8 bfr[4];
        #pragma unroll
        for (int n = 0; n < 4; ++n)
            bfr[n] = *(const bf16x8*)(smem + ((bCol[n] + ks * 64) ^ bXor[n]));
        #pragma unroll
        for (int m = 0; m < 2; ++m)
            #pragma unroll
            for (int n = 0; n < 4; ++n)
                acc[m][n] = __builtin_amdgcn_mfma_f32_16x16x32_bf16(
                    abuf[ks & 3][m], bfr[n], acc[m][n], 0, 0, 0);
    }

    __syncthreads();   // half-0 reads done; safe to overwrite

    // stage half 1
    #pragma unroll
    for (int i = 0; i < 6; ++i) {
        bf16x8 v = *(const bf16x8*)(ssrc0 + KHALF + i * 8);
        *(bf16x8*)(smem + ((sbase + i * 16) ^ sxor)) = v;
    }
    __syncthreads();   // half 1 ready

    #pragma unroll
    for (int ks = 6; ks < 12; ++ks) {
        if (ks + 3 < KTOT / 32) {
            #pragma unroll
            for (int m = 0; m < 2; ++m)
                abuf[(ks + 3) & 3][m] = LOAD_A(m, ks + 3);
        }
        bf16x8 bfr[4];
        #pragma unroll
        for (int n = 0; n < 4; ++n)
            bfr[n] = *(const bf16x8*)(smem + ((bCol[n] + (ks - 6) * 64) ^ bXor[n]));
        #pragma unroll
        for (int m = 0; m < 2; ++m)
            #pragma unroll
            for (int n = 0; n < 4; ++n)
                acc[m][n] = __builtin_amdgcn_mfma_f32_16x16x32_bf16(
                    abuf[ks & 3][m], bfr[n], acc[m][n], 0, 0, 0);
    }

    // ---- epilogue: de-interleave gates + GRU ----
    // ONE barrier to fence B-buffer aliasing; epi[wid] is per-wave after that
    // (intra-wave ds ordering is handled by the compiler's lgkmcnt waits).
    __syncthreads();

    int rc0 = nw >> 2;          // wave real-col base (16 real cols)
    int erow = lane >> 2;       // 0..15
    int g4 = lane & 3;          // 4 real cols per lane
    int cbase = rc0 + g4 * 4;
    float4 bi_r = *(const float4*)(b_ih + cbase);
    float4 bh_r = *(const float4*)(b_hh + cbase);
    float4 bi_z = *(const float4*)(b_ih + cbase + 128);
    float4 bh_z = *(const float4*)(b_hh + cbase + 128);
    float4 bi_n = *(const float4*)(b_ih + cbase + 256);
    float4 bh_n = *(const float4*)(b_hh + cbase + 256);

    #pragma unroll
    for (int m = 0; m < 2; ++m) {
        #pragma unroll
        for (int n = 0; n < 4; ++n)
            #pragma unroll
            for (int reg = 0; reg < 4; ++reg)
                epi[wid][kg * 4 + reg][n * 16 + rif] = acc[m][n][reg];

        float4 q0 = *(const float4*)&epi[wid][erow][g4 * 16 + 0];
        float4 q1 = *(const float4*)&epi[wid][erow][g4 * 16 + 4];
        float4 q2 = *(const float4*)&epi[wid][erow][g4 * 16 + 8];
        float4 q3 = *(const float4*)&epi[wid][erow][g4 * 16 + 12];

        int node = mw + m * 16 + erow;
        if (node < N_NODES) {
            float4 f = *(const float4*)(feat + (size_t)node * D + cbase);
            float4 res;
            {
                float r = 1.f / (1.f + __expf(-(q0.x + bi_r.x + bh_r.x)));
                float z = 1.f / (1.f + __expf(-(q0.y + bi_z.x + bh_z.x)));
                float ng = tanhf(q0.z + bi_n.x + r * (q0.w + bh_n.x));
                res.x = (1.f - z) * ng + z * f.x;
            }
            {
                float r = 1.f / (1.f + __expf(-(q1.x + bi_r.y + bh_r.y)));
                float z = 1.f / (1.f + __expf(-(q1.y + bi_z.y + bh_z.y)));
                float ng = tanhf(q1.z + bi_n.y + r * (q1.w + bh_n.y));
                res.y = (1.f - z) * ng + z * f.y;
            }
            {
                float r = 1.f / (1.f + __expf(-(q2.x + bi_r.z + bh_r.z)));
                float z = 1.f / (1.f + __expf(-(q2.y + bi_z.z + bh_z.z)));
                float ng = tanhf(q2.z + bi_n.z + r * (q2.w + bh_n.z));
                res.z = (1.f - z) * ng + z * f.z;
            }
            {
                float r = 1.f / (1.f + __expf(-(q3.x + bi_r.w + bh_r.w)));
                float z = 1.f / (1.f + __expf(-(q3.y + bi_z.w + bh_z.w)));
                float ng = tanhf(q3.z + bi_n.w + r * (q3.w + bh_n.w));
                res.w = (1.f - z) * ng + z * f.w;
            }
            *(float4*)(out + (size_t)node * D + cbase) = res;
        }
    }
}

// ===========================================================================
extern "C" void kernel_launch(void* const* d_in, const int* in_sizes, int n_in,
                              void* d_out, int out_size, void* d_ws, size_t ws_size,
                              hipStream_t stream) {
    const float* feat = (const float*)d_in[0];
    const int*   esrc = (const int*)d_in[1];
    const int*   edst = (const int*)d_in[2];
    const float* ew   = (const float*)d_in[3];
    const float* W1   = (const float*)d_in[4];
    const float* W2   = (const float*)d_in[5];
    const float* W_ih = (const float*)d_in[6];
    const float* W_hh = (const float*)d_in[7];
    const float* b_ih = (const float*)d_in[8];
    const float* b_hh = (const float*)d_in[9];
    float* out = (float*)d_out;

    const size_t AH2_ELEMS = (size_t)N_NODES * 256;  // u16
    const size_t FB_ELEMS  = (size_t)N_NODES * 128;  // u16
    const size_t needWords = (AH2_ELEMS + FB_ELEMS) / 2 + 2 * N_NODES
                           + 2 * (size_t)N_EDGES          // csr1+csr2
                           + 4 * (size_t)N_EDGES          // tmp1+tmp2 (uint2)
                           + 512 + 2 * (size_t)KTOT * D + (NCOLS * KTOT) / 2;
    if (ws_size < needWords * 4) {
        fill_sentinel<<<512, 256, 0, stream>>>(out, (long)out_size, 12345.0f);
        return;
    }

    u16*   Ah2  = (u16*)d_ws;
    u16*   fb16 = Ah2 + AH2_ELEMS;
    int*   off1 = (int*)(fb16 + FB_ELEMS);
    int*   off2 = off1 + N_NODES;
    u32*   csr1 = (u32*)(off2 + N_NODES);
    u32*   csr2 = csr1 + N_EDGES;
    uint2* tmp1 = (uint2*)(csr2 + N_EDGES);
    uint2* tmp2 = tmp1 + N_EDGES;
    int*   bsum = (int*)(tmp2 + N_EDGES);    // 256
    int*   bks  = bsum + 256;                // 256
    float* M1   = (float*)(bks + 256);
    float* M2   = M1 + KTOT * D;
    u16*   Bt   = (u16*)(M2 + KTOT * D);

    const int EB = (N_EDGES + 255) / 256;

    front<<<2048, 256, 0, stream>>>(feat, fb16, (u32*)off1);
    count_both<<<EB, 256, 0, stream>>>(esrc, edst, off1, off2);
    scan_partial<<<dim3(SCAN_NB, 2), 256, 0, stream>>>(off1, bsum);
    scan_bsums<<<1, 256, 0, stream>>>(bsum);
    scan_final<<<dim3(SCAN_NB, 2), 256, 0, stream>>>(off1, bsum);

    init_buckets<<<1, 64, 0, stream>>>(off1, off2, bks);
    partA<<<dim3(PA_NB, 2), 256, 0, stream>>>(esrc, edst, ew, bks, tmp1, tmp2);
    partB<<<dim3(NBUCKETS, 2), 256, 0, stream>>>(
        tmp1, tmp2, bks, off1, off2, csr1, csr2);

    gather_both<<<(2 * N_NODES * 64 + 127) / 128, 128, 0, stream>>>(
        Ah2, fb16, off1, csr1, off2, csr2);

    compute_M<<<dim3(KTOT, 2), 128, 0, stream>>>(W_ih, W1, W2, M1, M2);
    fill_Bt<<<(NCOLS * KTOT + 255) / 256, 256, 0, stream>>>(M1, M2, W_hh, Bt);

    gemm_gru_mfma<<<GEMM_NWG, 256, 0, stream>>>(Ah2, fb16, Bt, feat, b_ih, b_hh, out);
}

// Round 21
// 206.494 us; speedup vs baseline: 1.0756x; 1.0081x over previous
//
#include <hip/hip_runtime.h>
#include <math.h>

#define N_NODES 50000
#define N_EDGES 600000
#define D 128
#define KTOT 384    // 3*D  (k: [n1 | n2 | feat])
#define NCOLS 512   // 4*D  (gate-interleaved cols: c' = 4c+g)

#define SCAN_CHUNK 512
#define SCAN_NB ((N_NODES + SCAN_CHUNK - 1) / SCAN_CHUNK)   // 98

#define GEMM_ROWB ((N_NODES + 127) / 128)    // 391 row panels
#define GEMM_NWG  (GEMM_ROWB * 8)            // 3128 blocks, 8 col-blocks
#define NXCD 8
#define KHALF 192                            // K per LDS stage

// binned CSR build
#define BSHIFT 10
#define BSIZE (1 << BSHIFT)
#define NBUCKETS ((N_NODES + BSIZE - 1) >> BSHIFT)           // 49
#define PA_NB 512
#define PA_CHUNK ((N_EDGES + PA_NB - 1) / PA_NB)             // 1172

typedef unsigned int u32;
typedef unsigned short u16;

typedef __attribute__((ext_vector_type(8))) short bf16x8;   // 8 bf16 (4 VGPRs)
typedef __attribute__((ext_vector_type(4))) float f32x4;

__device__ __forceinline__ float bits2f(u32 u) {
    float f; __builtin_memcpy(&f, &u, 4);
    return f;
}
__device__ __forceinline__ u16 f2b(float f) {   // RNE bf16
    u32 u; __builtin_memcpy(&u, &f, 4);
    u32 r = (u + 0x7fffu + ((u >> 16) & 1u)) >> 16;
    return (u16)r;
}

// ---------------------------------------------------------------------------
__global__ void fill_sentinel(float* __restrict__ p, long n, float v) {
    long i = (long)blockIdx.x * blockDim.x + threadIdx.x;
    long stride = (long)gridDim.x * blockDim.x;
    for (; i < n; i += stride) p[i] = v;
}

// ---------------------------------------------------------------------------
// Front: zero degree counters AND convert feat fp32 -> bf16 into fb16[N][128].
// ---------------------------------------------------------------------------
__global__ void front(const float* __restrict__ feat, u16* __restrict__ fb16,
                      u32* __restrict__ offz) {
    long stride = (long)gridDim.x * blockDim.x;
    long t0 = (long)blockIdx.x * blockDim.x + threadIdx.x;
    for (long i = t0; i < 2 * N_NODES; i += stride) offz[i] = 0u;
    for (long i = t0; i < (long)N_NODES * (D / 4); i += stride) {
        int n = (int)(i >> 5), j4 = (int)(i & 31);
        float4 v = *(const float4*)(feat + (size_t)n * D + j4 * 4);
        ushort4 o;
        o.x = f2b(v.x); o.y = f2b(v.y); o.z = f2b(v.z); o.w = f2b(v.w);
        *(ushort4*)(fb16 + ((size_t)n << 7) + j4 * 4) = o;
    }
}

// ---------------------------------------------------------------------------
// CSR build step 1: degree count (both directions).
// ---------------------------------------------------------------------------
__global__ void count_both(const int* __restrict__ esrc, const int* __restrict__ edst,
                           int* __restrict__ cnt1, int* __restrict__ cnt2) {
    int e = blockIdx.x * blockDim.x + threadIdx.x;
    if (e < N_EDGES) {
        atomicAdd(&cnt1[edst[e]], 1);
        atomicAdd(&cnt2[esrc[e]], 1);
    }
}

// Phase 1: per-block chunk sums. grid (SCAN_NB, 2), 256 threads, 2 elems/thread.
__global__ void scan_partial(const int* __restrict__ off, int* __restrict__ bsum) {
    int dir = blockIdx.y, bx = blockIdx.x, t = threadIdx.x;
    const int* a = off + (size_t)dir * N_NODES;
    int i0 = bx * SCAN_CHUNK + 2 * t;
    int s = 0;
    if (i0 < N_NODES) s += a[i0];
    if (i0 + 1 < N_NODES) s += a[i0 + 1];
    __shared__ int red[256];
    red[t] = s;
    __syncthreads();
    for (int d = 128; d > 0; d >>= 1) {
        if (t < d) red[t] += red[t + d];
        __syncthreads();
    }
    if (t == 0) bsum[dir * SCAN_NB + bx] = red[0];
}

// Phase 2: exclusive scan of the two bsum segments (one block, two halves).
__global__ void scan_bsums(int* __restrict__ bsum) {
    __shared__ int part[256];
    int t = threadIdx.x;
    int i = t & 127, dir = t >> 7;
    int v = (i < SCAN_NB) ? bsum[dir * SCAN_NB + i] : 0;
    part[t] = v;
    __syncthreads();
    for (int d = 1; d < 128; d <<= 1) {
        int add = (i >= d) ? part[t - d] : 0;
        __syncthreads();
        part[t] += add;
        __syncthreads();
    }
    if (i < SCAN_NB) bsum[dir * SCAN_NB + i] = part[t] - v;  // exclusive
}

// Phase 3: in-place exclusive scan of each chunk + block base -> off[n]=start(n).
// ALSO writes the bucket-bound table bks (absorbs init_buckets): the thread
// whose i0 is a multiple of BSIZE holds that bucket's start in-register.
__global__ void scan_final(int* __restrict__ off, const int* __restrict__ bsum,
                           int* __restrict__ bks) {
    int dir = blockIdx.y, bx = blockIdx.x, t = threadIdx.x;
    int* a = off + (size_t)dir * N_NODES;
    int base = bsum[dir * SCAN_NB + bx];
    int i0 = bx * SCAN_CHUNK + 2 * t;
    int e0 = (i0 < N_NODES) ? a[i0] : 0;
    int e1 = (i0 + 1 < N_NODES) ? a[i0 + 1] : 0;
    __shared__ int part[256];
    int v = e0 + e1;
    part[t] = v;
    __syncthreads();
    for (int d = 1; d < 256; d <<= 1) {
        int add = (t >= d) ? part[t - d] : 0;
        __syncthreads();
        part[t] += add;
        __syncthreads();
    }
    int tb = base + part[t] - v;   // exclusive prefix for this thread
    if (i0 < N_NODES) a[i0] = tb;
    if (i0 + 1 < N_NODES) a[i0 + 1] = tb + e0;
    // bucket bounds: i0 multiple of BSIZE -> bucket b = i0>>BSHIFT starts at tb
    if (i0 < N_NODES && (i0 & (BSIZE - 1)) == 0) {
        int b = i0 >> BSHIFT;
        int* bk = bks + dir * 128;
        bk[b] = tb;            // start
        bk[64 + b] = tb;       // fill (working copy)
    }
    if (bx == 0 && t == 0) {
        bks[dir * 128 + NBUCKETS] = N_EDGES;   // sentinel end
    }
}

// ---------------------------------------------------------------------------
// Phase A (both dirs fused, blockIdx.y = dir): partition edges into coarse
// buckets via LDS histogram + staging; flush per-bucket runs to tmp.
// Staged entry embeds the bucket id -> flush is ONE LDS read, no search.
// ---------------------------------------------------------------------------
__global__ __launch_bounds__(256)
void partA(const int* __restrict__ esrc, const int* __restrict__ edst,
           const float* __restrict__ ew, int* __restrict__ bks,
           uint2* __restrict__ tmp1, uint2* __restrict__ tmp2) {
    __shared__ int lcnt[NBUCKETS];
    __shared__ int lbase[NBUCKETS + 1];
    __shared__ int gbase[NBUCKETS];
    __shared__ uint2 stage[PA_CHUNK];
    int dir = blockIdx.y;
    const int* key = dir ? esrc : edst;
    const int* nbr = dir ? edst : esrc;
    int* bucketFill = bks + dir * 128 + 64;
    uint2* tmp = dir ? tmp2 : tmp1;

    int t = threadIdx.x;
    int e0 = blockIdx.x * PA_CHUNK;
    int e1 = min(e0 + PA_CHUNK, N_EDGES);
    if (t < NBUCKETS) lcnt[t] = 0;
    __syncthreads();
    for (int e = e0 + t; e < e1; e += 256)
        atomicAdd(&lcnt[key[e] >> BSHIFT], 1);
    __syncthreads();
    if (t == 0) {
        int s = 0;
        for (int b = 0; b < NBUCKETS; ++b) { lbase[b] = s; s += lcnt[b]; }
        lbase[NBUCKETS] = s;
    }
    __syncthreads();
    if (t < NBUCKETS) {
        gbase[t] = atomicAdd(&bucketFill[t], lcnt[t]);
        lcnt[t] = 0;    // reuse as fill
    }
    __syncthreads();
    for (int e = e0 + t; e < e1; e += 256) {
        int k = key[e];
        int b = k >> BSHIFT;
        int i = lbase[b] + atomicAdd(&lcnt[b], 1);
        u32 wb = (u32)f2b(ew[e]);
        stage[i] = make_uint2(((u32)k << 16) | (u32)nbr[e], ((u32)b << 16) | wb);
    }
    __syncthreads();
    int total = lbase[NBUCKETS];
    for (int i = t; i < total; i += 256) {
        uint2 v = stage[i];
        int b = (int)(v.y >> 16);
        tmp[gbase[b] + (i - lbase[b])] = make_uint2(v.x, v.y & 0xffffu);
    }
}

// ---------------------------------------------------------------------------
// Phase B: ONE block per (bucket, dir). LDS-claimed slots; all writes of a
// bucket flow through one CU -> one XCD L2 -> ~1x write amplification.
// ---------------------------------------------------------------------------
__global__ __launch_bounds__(256)
void partB(const uint2* __restrict__ tmp1, const uint2* __restrict__ tmp2,
           const int* __restrict__ bks,
           const int* __restrict__ off1, const int* __restrict__ off2,
           u32* __restrict__ csr1, u32* __restrict__ csr2) {
    __shared__ int lcnt[BSIZE];
    __shared__ int loff[BSIZE];
    int dir = blockIdx.y;
    const uint2* tmp = dir ? tmp2 : tmp1;
    const int* bucketStart = bks + dir * 128;
    const int* off = dir ? off2 : off1;
    u32* csr = dir ? csr2 : csr1;

    int b = blockIdx.x;
    int s = bucketStart[b], e = bucketStart[b + 1];
    int nbase = b << BSHIFT;
    for (int i = threadIdx.x; i < BSIZE; i += 256) {
        lcnt[i] = 0;
        int nn = nbase + i;
        loff[i] = (nn < N_NODES) ? off[nn] : 0;
    }
    __syncthreads();
    for (int i = s + (int)threadIdx.x; i < e; i += 256) {
        uint2 v = tmp[i];
        int li = (v.x >> 16) & (BSIZE - 1);
        int p = loff[li] + atomicAdd(&lcnt[li], 1);
        csr[p] = ((v.x & 0xffffu) << 16) | (v.y & 0xffffu);
    }
}

// ---------------------------------------------------------------------------
// Fused gather-aggregate. One wave per (node, dir); TWO edges per half-wave
// step, 8 edges in flight. 128-thread blocks. off holds STARTS.
// ---------------------------------------------------------------------------
__global__ __launch_bounds__(128)
void gather_both(u16* __restrict__ Ah2, const u16* __restrict__ fb16,
                 const int* __restrict__ off1, const u32* __restrict__ csr1,
                 const int* __restrict__ off2, const u32* __restrict__ csr2) {
    int gw = (blockIdx.x * blockDim.x + threadIdx.x) >> 6;
    int lane = threadIdx.x & 63;
    if (gw >= 2 * N_NODES) return;
    int dir = (gw >= N_NODES);
    int n = dir ? gw - N_NODES : gw;
    const int* off = dir ? off2 : off1;
    const u32* csr = dir ? csr2 : csr1;
    int start = off[n];
    int end = (n + 1 < N_NODES) ? off[n + 1] : N_EDGES;
    int half = lane >> 5;
    int hl = lane & 31;
    const u16* fbl = fb16 + hl * 4;
    float a0 = 0.f, a1 = 0.f, a2 = 0.f, a3 = 0.f, sw = 0.f;
    int p = start;
    for (; p + 7 < end; p += 8) {
        u32 cA = csr[p + half],     cB = csr[p + 2 + half];
        u32 cC = csr[p + 4 + half], cD = csr[p + 6 + half];
        uint2 vA = *(const uint2*)(fbl + ((size_t)(cA >> 16) << 7));
        uint2 vB = *(const uint2*)(fbl + ((size_t)(cB >> 16) << 7));
        uint2 vC = *(const uint2*)(fbl + ((size_t)(cC >> 16) << 7));
        uint2 vD = *(const uint2*)(fbl + ((size_t)(cD >> 16) << 7));
        float wA = bits2f(cA << 16), wB = bits2f(cB << 16);
        float wC = bits2f(cC << 16), wD = bits2f(cD << 16);
        a0 += bits2f(vA.x << 16) * wA + bits2f(vB.x << 16) * wB
            + bits2f(vC.x << 16) * wC + bits2f(vD.x << 16) * wD;
        a1 += bits2f(vA.x & 0xffff0000u) * wA + bits2f(vB.x & 0xffff0000u) * wB
            + bits2f(vC.x & 0xffff0000u) * wC + bits2f(vD.x & 0xffff0000u) * wD;
        a2 += bits2f(vA.y << 16) * wA + bits2f(vB.y << 16) * wB
            + bits2f(vC.y << 16) * wC + bits2f(vD.y << 16) * wD;
        a3 += bits2f(vA.y & 0xffff0000u) * wA + bits2f(vB.y & 0xffff0000u) * wB
            + bits2f(vC.y & 0xffff0000u) * wC + bits2f(vD.y & 0xffff0000u) * wD;
        sw += wA + wB + wC + wD;
    }
    for (; p + 3 < end; p += 4) {
        u32 cA = csr[p + half], cB = csr[p + 2 + half];
        uint2 vA = *(const uint2*)(fbl + ((size_t)(cA >> 16) << 7));
        uint2 vB = *(const uint2*)(fbl + ((size_t)(cB >> 16) << 7));
        float wA = bits2f(cA << 16), wB = bits2f(cB << 16);
        a0 += bits2f(vA.x << 16) * wA + bits2f(vB.x << 16) * wB;
        a1 += bits2f(vA.x & 0xffff0000u) * wA + bits2f(vB.x & 0xffff0000u) * wB;
        a2 += bits2f(vA.y << 16) * wA + bits2f(vB.y << 16) * wB;
        a3 += bits2f(vA.y & 0xffff0000u) * wA + bits2f(vB.y & 0xffff0000u) * wB;
        sw += wA + wB;
    }
    for (; p < end; p += 2) {
        u32 c = (p + half < end) ? csr[p + half] : 0u;   // c=0 -> w=0, row 0
        uint2 v = *(const uint2*)(fbl + ((size_t)(c >> 16) << 7));
        float w = bits2f(c << 16);
        a0 += bits2f(v.x << 16) * w;
        a1 += bits2f(v.x & 0xffff0000u) * w;
        a2 += bits2f(v.y << 16) * w;
        a3 += bits2f(v.y & 0xffff0000u) * w;
        sw += w;
    }
    a0 += __shfl_xor(a0, 32);
    a1 += __shfl_xor(a1, 32);
    a2 += __shfl_xor(a2, 32);
    a3 += __shfl_xor(a3, 32);
    sw += __shfl_xor(sw, 32);
    if (lane < 32) {
        float inv = (sw > 0.f) ? 1.f / sw : 0.f;
        if (!isfinite(inv)) inv = 0.f;
        uint2 o;
        o.x = ((u32)f2b(a1 * inv) << 16) | (u32)f2b(a0 * inv);
        o.y = ((u32)f2b(a3 * inv) << 16) | (u32)f2b(a2 * inv);
        *(uint2*)(Ah2 + ((size_t)n << 8) + dir * 128 + hl * 4) = o;
    }
}

// ---------------------------------------------------------------------------
// Weight folding: M1 = W_ih[:, :128] @ W1 ; M2 = W_ih[:, 128:] @ W2 (fp32).
// ---------------------------------------------------------------------------
__global__ void compute_M(const float* __restrict__ W_ih,
                          const float* __restrict__ W1,
                          const float* __restrict__ W2,
                          float* __restrict__ M1, float* __restrict__ M2) {
    int r = blockIdx.x;          // 0..383
    int k = threadIdx.x;         // 0..127
    int which = blockIdx.y;
    const float* Wsel = which ? W2 : W1;
    const float* ih = W_ih + (size_t)r * (2 * D) + which * D;
    float acc = 0.f;
    for (int j = 0; j < D; ++j) acc += ih[j] * Wsel[j * D + k];
    (which ? M2 : M1)[r * D + k] = acc;
}

// ---------------------------------------------------------------------------
// Bt [512 cols][384 k] bf16, k-contiguous rows. Col c' = 4c+g:
//   g=0: r-sum rows c (M1|M2|W_hh); g=1: z-sum rows c+128;
//   g=2: gi_n rows c+256 (M1|M2|0); g=3: gh_n (0|0|W_hh row c+256)
// ---------------------------------------------------------------------------
__global__ void fill_Bt(const float* __restrict__ M1, const float* __restrict__ M2,
                        const float* __restrict__ W_hh, u16* __restrict__ Bt) {
    int idx = blockIdx.x * blockDim.x + threadIdx.x;
    if (idx >= NCOLS * KTOT) return;
    int cp = idx / KTOT;
    int k  = idx - cp * KTOT;
    int c = cp >> 2, g = cp & 3;
    float v = 0.f;
    if (g <= 1) {
        int r = c + (g == 1 ? 128 : 0);
        v = (k < 128) ? M1[r * D + k]
          : (k < 256) ? M2[r * D + (k - 128)]
                      : W_hh[r * D + (k - 256)];
    } else if (g == 2) {
        int r = c + 256;
        v = (k < 128) ? M1[r * D + k]
          : (k < 256) ? M2[r * D + (k - 128)] : 0.f;
    } else {
        v = (k >= 256) ? W_hh[(c + 256) * D + (k - 256)] : 0.f;
    }
    if (!isfinite(v)) v = 0.f;
    Bt[idx] = f2b(v);
}

// ---------------------------------------------------------------------------
// MFMA GEMM + fused GRU, v8b (round-20 verified): 32x64 wave tile, two-half
// B staging in 24 KB LDS, pow2-stride A tables, depth-4 A ring, XOR swizzle
// on full offset both sides (rule #21), single-barrier epilogue.
// ---------------------------------------------------------------------------
#define LOAD_A(m, k) ((k) < 8 ? *(const bf16x8*)(aP[m] + (k) * 32) \
                              : *(const bf16x8*)(fP[m] + ((k) - 8) * 32))

__global__ __launch_bounds__(256)
void gemm_gru_mfma(const u16* __restrict__ Ah2, const u16* __restrict__ fb16,
                   const u16* __restrict__ Bt, const float* __restrict__ feat,
                   const float* __restrict__ b_ih, const float* __restrict__ b_hh,
                   float* __restrict__ out) {
    __shared__ __align__(16) char smem[64 * KHALF * 2];  // 24 KB: B half / epi
    float (*epi)[16][65] = (float(*)[16][65])smem;       // aliases B (dead later)

    int bid = blockIdx.x;
    int wgid = (bid % NXCD) * (GEMM_NWG / NXCD) + bid / NXCD;   // bijective
    int rowp = wgid >> 3;
    int colb = wgid & 7;
    int tid = threadIdx.x, lane = tid & 63, wid = tid >> 6;
    int mw = rowp * 128 + wid * 32;         // wave row (node) base
    int nw = colb * 64;                     // block gate-col base (all waves)
    int rif = lane & 15, kg = lane >> 4;

    // staging geometry (per half): each thread 6 x b128
    int scol = tid >> 2;                   // 0..63
    int sq   = tid & 3;                    // 0..3 -> 48-k quarter
    u32 sbase = (u32)scol * (KHALF * 2) + (u32)sq * 96;
    u32 sxor  = (u32)((scol & 7) << 4);
    const u16* ssrc0 = Bt + (size_t)(nw + scol) * KTOT + sq * 48;

    // B read: col base within half; XOR applied to FULL offset (rule #21).
    u32 bCol[4], bXor[4];
    #pragma unroll
    for (int n = 0; n < 4; ++n) {
        u32 col = n * 16 + rif;
        bCol[n] = col * (KHALF * 2) + kg * 16;
        bXor[n] = (col & 7) << 4;
    }

    f32x4 acc[2][4];
    #pragma unroll
    for (int m = 0; m < 2; ++m)
        #pragma unroll
        for (int n = 0; n < 4; ++n)
            acc[m][n] = (f32x4){0.f, 0.f, 0.f, 0.f};

    const u16* aP[2];
    const u16* fP[2];
    #pragma unroll
    for (int m = 0; m < 2; ++m) {
        int arow = min(mw + m * 16 + rif, N_NODES - 1);
        aP[m] = Ah2 + ((size_t)arow << 8) + kg * 8;
        fP[m] = fb16 + ((size_t)arow << 7) + kg * 8;
    }

    // stage half 0
    #pragma unroll
    for (int i = 0; i < 6; ++i) {
        bf16x8 v = *(const bf16x8*)(ssrc0 + i * 8);
        *(bf16x8*)(smem + ((sbase + i * 16) ^ sxor)) = v;
    }

    // depth-4 A prefetch ring (fully unrolled -> static indices)
    bf16x8 abuf[4][2];
    #pragma unroll
    for (int s = 0; s < 3; ++s)
        #pragma unroll
        for (int m = 0; m < 2; ++m)
            abuf[s][m] = LOAD_A(m, s);

    __syncthreads();   // half 0 ready

    #pragma unroll
    for (int ks = 0; ks < 6; ++ks) {
        if (ks + 3 < KTOT / 32) {
            #pragma unroll
            for (int m = 0; m < 2; ++m)
                abuf[(ks + 3) & 3][m] = LOAD_A(m, ks + 3);
        }
        bf16x8 bfr[4];
        #pragma unroll
        for (int n = 0; n < 4; ++n)
            bfr[n] = *(const bf16x8*)(smem + ((bCol[n] + ks * 64) ^ bXor[n]));
        #pragma unroll
        for (int m = 0; m < 2; ++m)
            #pragma unroll
            for (int n = 0; n < 4; ++n)
                acc[m][n] = __builtin_amdgcn_mfma_f32_16x16x32_bf16(
                    abuf[ks & 3][m], bfr[n], acc[m][n], 0, 0, 0);
    }

    __syncthreads();   // half-0 reads done; safe to overwrite

    // stage half 1
    #pragma unroll
    for (int i = 0; i < 6; ++i) {
        bf16x8 v = *(const bf16x8*)(ssrc0 + KHALF + i * 8);
        *(bf16x8*)(smem + ((sbase + i * 16) ^ sxor)) = v;
    }
    __syncthreads();   // half 1 ready

    #pragma unroll
    for (int ks = 6; ks < 12; ++ks) {
        if (ks + 3 < KTOT / 32) {
            #pragma unroll
            for (int m = 0; m < 2; ++m)
                abuf[(ks + 3) & 3][m] = LOAD_A(m, ks + 3);
        }
        bf16x8 bfr[4];
        #pragma unroll
        for (int n = 0; n < 4; ++n)
            bfr[n] = *(const bf16x8*)(smem + ((bCol[n] + (ks - 6) * 64) ^ bXor[n]));
        #pragma unroll
        for (int m = 0; m < 2; ++m)
            #pragma unroll
            for (int n = 0; n < 4; ++n)
                acc[m][n] = __builtin_amdgcn_mfma_f32_16x16x32_bf16(
                    abuf[ks & 3][m], bfr[n], acc[m][n], 0, 0, 0);
    }

    // ---- epilogue: de-interleave gates + GRU ----
    __syncthreads();   // fence B-buffer aliasing; epi[wid] is per-wave after

    int rc0 = nw >> 2;          // wave real-col base (16 real cols)
    int erow = lane >> 2;       // 0..15
    int g4 = lane & 3;          // 4 real cols per lane
    int cbase = rc0 + g4 * 4;
    float4 bi_r = *(const float4*)(b_ih + cbase);
    float4 bh_r = *(const float4*)(b_hh + cbase);
    float4 bi_z = *(const float4*)(b_ih + cbase + 128);
    float4 bh_z = *(const float4*)(b_hh + cbase + 128);
    float4 bi_n = *(const float4*)(b_ih + cbase + 256);
    float4 bh_n = *(const float4*)(b_hh + cbase + 256);

    #pragma unroll
    for (int m = 0; m < 2; ++m) {
        #pragma unroll
        for (int n = 0; n < 4; ++n)
            #pragma unroll
            for (int reg = 0; reg < 4; ++reg)
                epi[wid][kg * 4 + reg][n * 16 + rif] = acc[m][n][reg];

        float4 q0 = *(const float4*)&epi[wid][erow][g4 * 16 + 0];
        float4 q1 = *(const float4*)&epi[wid][erow][g4 * 16 + 4];
        float4 q2 = *(const float4*)&epi[wid][erow][g4 * 16 + 8];
        float4 q3 = *(const float4*)&epi[wid][erow][g4 * 16 + 12];

        int node = mw + m * 16 + erow;
        if (node < N_NODES) {
            float4 f = *(const float4*)(feat + (size_t)node * D + cbase);
            float4 res;
            {
                float r = 1.f / (1.f + __expf(-(q0.x + bi_r.x + bh_r.x)));
                float z = 1.f / (1.f + __expf(-(q0.y + bi_z.x + bh_z.x)));
                float ng = tanhf(q0.z + bi_n.x + r * (q0.w + bh_n.x));
                res.x = (1.f - z) * ng + z * f.x;
            }
            {
                float r = 1.f / (1.f + __expf(-(q1.x + bi_r.y + bh_r.y)));
                float z = 1.f / (1.f + __expf(-(q1.y + bi_z.y + bh_z.y)));
                float ng = tanhf(q1.z + bi_n.y + r * (q1.w + bh_n.y));
                res.y = (1.f - z) * ng + z * f.y;
            }
            {
                float r = 1.f / (1.f + __expf(-(q2.x + bi_r.z + bh_r.z)));
                float z = 1.f / (1.f + __expf(-(q2.y + bi_z.z + bh_z.z)));
                float ng = tanhf(q2.z + bi_n.z + r * (q2.w + bh_n.z));
                res.z = (1.f - z) * ng + z * f.z;
            }
            {
                float r = 1.f / (1.f + __expf(-(q3.x + bi_r.w + bh_r.w)));
                float z = 1.f / (1.f + __expf(-(q3.y + bi_z.w + bh_z.w)));
                float ng = tanhf(q3.z + bi_n.w + r * (q3.w + bh_n.w));
                res.w = (1.f - z) * ng + z * f.w;
            }
            *(float4*)(out + (size_t)node * D + cbase) = res;
        }
    }
}

// ===========================================================================
extern "C" void kernel_launch(void* const* d_in, const int* in_sizes, int n_in,
                              void* d_out, int out_size, void* d_ws, size_t ws_size,
                              hipStream_t stream) {
    const float* feat = (const float*)d_in[0];
    const int*   esrc = (const int*)d_in[1];
    const int*   edst = (const int*)d_in[2];
    const float* ew   = (const float*)d_in[3];
    const float* W1   = (const float*)d_in[4];
    const float* W2   = (const float*)d_in[5];
    const float* W_ih = (const float*)d_in[6];
    const float* W_hh = (const float*)d_in[7];
    const float* b_ih = (const float*)d_in[8];
    const float* b_hh = (const float*)d_in[9];
    float* out = (float*)d_out;

    const size_t AH2_ELEMS = (size_t)N_NODES * 256;  // u16
    const size_t FB_ELEMS  = (size_t)N_NODES * 128;  // u16
    const size_t needWords = (AH2_ELEMS + FB_ELEMS) / 2 + 2 * N_NODES
                           + 2 * (size_t)N_EDGES          // csr1+csr2
                           + 4 * (size_t)N_EDGES          // tmp1+tmp2 (uint2)
                           + 512 + 2 * (size_t)KTOT * D + (NCOLS * KTOT) / 2;
    if (ws_size < needWords * 4) {
        fill_sentinel<<<512, 256, 0, stream>>>(out, (long)out_size, 12345.0f);
        return;
    }

    u16*   Ah2  = (u16*)d_ws;
    u16*   fb16 = Ah2 + AH2_ELEMS;
    int*   off1 = (int*)(fb16 + FB_ELEMS);
    int*   off2 = off1 + N_NODES;
    u32*   csr1 = (u32*)(off2 + N_NODES);
    u32*   csr2 = csr1 + N_EDGES;
    uint2* tmp1 = (uint2*)(csr2 + N_EDGES);
    uint2* tmp2 = tmp1 + N_EDGES;
    int*   bsum = (int*)(tmp2 + N_EDGES);    // 256
    int*   bks  = bsum + 256;                // 256
    float* M1   = (float*)(bks + 256);
    float* M2   = M1 + KTOT * D;
    u16*   Bt   = (u16*)(M2 + KTOT * D);

    const int EB = (N_EDGES + 255) / 256;

    front<<<2048, 256, 0, stream>>>(feat, fb16, (u32*)off1);
    count_both<<<EB, 256, 0, stream>>>(esrc, edst, off1, off2);
    scan_partial<<<dim3(SCAN_NB, 2), 256, 0, stream>>>(off1, bsum);
    scan_bsums<<<1, 256, 0, stream>>>(bsum);
    scan_final<<<dim3(SCAN_NB, 2), 256, 0, stream>>>(off1, bsum, bks);

    partA<<<dim3(PA_NB, 2), 256, 0, stream>>>(esrc, edst, ew, bks, tmp1, tmp2);
    partB<<<dim3(NBUCKETS, 2), 256, 0, stream>>>(
        tmp1, tmp2, bks, off1, off2, csr1, csr2);

    gather_both<<<(2 * N_NODES * 64 + 127) / 128, 128, 0, stream>>>(
        Ah2, fb16, off1, csr1, off2, csr2);

    compute_M<<<dim3(KTOT, 2), 128, 0, stream>>>(W_ih, W1, W2, M1, M2);
    fill_Bt<<<(NCOLS * KTOT + 255) / 256, 256, 0, stream>>>(M1, M2, W_hh, Bt);

    gemm_gru_mfma<<<GEMM_NWG, 256, 0, stream>>>(Ah2, fb16, Bt, feat, b_ih, b_hh, out);
}